// Round 15
// baseline (111.398 us; speedup 1.0000x reference)
//
#include <hip/hip_runtime.h>
#include <hip/hip_bf16.h>

#define SEQ 8192
#define HD 128
#define BM 256
#define BN 64
#define NQT (SEQ / BM)   // 32
#define THREADS 512

typedef __bf16 bf16_t;
typedef __bf16 bf16x2 __attribute__((ext_vector_type(2)));
typedef __bf16 bf16x8 __attribute__((ext_vector_type(8)));
typedef float f32x4 __attribute__((ext_vector_type(4)));
typedef float f32x16 __attribute__((ext_vector_type(16)));
typedef unsigned int u32x4 __attribute__((ext_vector_type(4)));

#if __has_builtin(__builtin_amdgcn_exp2f)
__device__ inline float exp2_fast(float x) { return __builtin_amdgcn_exp2f(x); }
#else
__device__ inline float exp2_fast(float x) { return exp2f(x); }
#endif

// v_permlane32_swap_b32: a.hi32lanes <-> b.lo32lanes (one VALU op; replaces
// ds_bpermute round-trip + cndmask selects for the half-wave exchange).
// Mapping verified by R9 pass.
__device__ inline void permswap32(unsigned int& a, unsigned int& b) {
#if __has_builtin(__builtin_amdgcn_permlane32_swap)
  auto r = __builtin_amdgcn_permlane32_swap(a, b, false, false);
  a = (unsigned int)r[0];
  b = (unsigned int)r[1];
#else
  asm volatile("v_permlane32_swap_b32 %0, %1" : "+v"(a), "+v"(b));
#endif
}

// async global->LDS DMA, 16 B per lane; lds dest wave-uniform, HW adds lane*16
__device__ inline void load_lds16(const void* g, void* l) {
  __builtin_amdgcn_global_load_lds(
      (const __attribute__((address_space(1))) void*)g,
      (__attribute__((address_space(3))) void*)l, 16, 0, 0);
}

// ---------------- prep ----------------
// Kb blocked: [tile T][d-chunk c 0..15][key r 0..63][8]  = K[T*64+r][c*8+j]
// VT blocked: [tile T][key-chunk kc 0..7][d 0..127][8]   = V[T*64+kc*8+j][d]
__global__ __launch_bounds__(256) void prep_kernel(const float* __restrict__ K,
                                                   const float* __restrict__ V,
                                                   bf16_t* __restrict__ Kb,
                                                   bf16_t* __restrict__ VT) {
  const int b = (int)blockIdx.x;
  const int tid = (int)threadIdx.x;
  if (b < 256) {
    // V tile: 64 keys x 64 d, staged f32 in LDS (coalesced reads)
    __shared__ float tile[64][65];
    const int T = b & 127;
    const int d0 = (b >> 7) * 64;
    const int s0 = T * 64;
    const int r = tid >> 2;          // 0..63 (key)
    const int c0 = (tid & 3) * 16;   // d offset
#pragma unroll
    for (int j4 = 0; j4 < 4; ++j4) {
      float4 x = *(const float4*)&V[(size_t)(s0 + r) * HD + d0 + c0 + j4 * 4];
      tile[r][c0 + j4 * 4 + 0] = x.x;
      tile[r][c0 + j4 * 4 + 1] = x.y;
      tile[r][c0 + j4 * 4 + 2] = x.z;
      tile[r][c0 + j4 * 4 + 3] = x.w;
    }
    __syncthreads();
    const int d_l = tid & 63;
    const int kc0 = (tid >> 6) * 2;  // 0,2,4,6
#pragma unroll
    for (int k2 = 0; k2 < 2; ++k2) {
      const int kc = kc0 + k2;
      bf16x8 wv;
#pragma unroll
      for (int j = 0; j < 8; ++j) wv[j] = (bf16_t)tile[kc * 8 + j][d_l];
      *(bf16x8*)&VT[((size_t)(T * 8 + kc) * 128 + d0 + d_l) * 8] = wv;
    }
  } else {
    // K convert: one 16B chunk per thread
    const int base = (b - 256) * 2048 + tid * 8;   // flat over 8192*128
    const int row = base >> 7;
    const int c = (base >> 3) & 15;
    const int T = row >> 6;
    const int r = row & 63;
    float4 a = *(const float4*)&K[base];
    float4 cc = *(const float4*)&K[base + 4];
    bf16x8 f;
    f[0] = (bf16_t)a.x; f[1] = (bf16_t)a.y; f[2] = (bf16_t)a.z; f[3] = (bf16_t)a.w;
    f[4] = (bf16_t)cc.x; f[5] = (bf16_t)cc.y; f[6] = (bf16_t)cc.z; f[7] = (bf16_t)cc.w;
    *(bf16x8*)&Kb[((size_t)(T * 16 + c) * 64 + r) * 8] = f;
  }
}

// ---------------- main flash-attention kernel ----------------
// FINAL (= R9, best of 15 rounds: fattn ~44.0 us, total ~110.3 us).
// BM=256, 8 waves, wave w owns 32 q-rows x all keys x all d. Cross-tile
// pipeline: iteration it does DMA(it+1), QK^T(it), PV(it-1) chunks
// textually interleaved with exp/pack(it), one barrier/iter. P stays in
// registers via permlane32_swap half-wave exchange (pure VALU).
//
// Structural ceiling (measured over R10-R14): LDS b128-read throughput is
// the widest pipe (256 reads/CU-iter ~= 47% busy; matrix issue-busy ~8% --
// MfmaUtil's 30% is latency-inclusive). Closing the remaining 2x gap to
// the LDS floor needs >=4 waves/SIMD (TLP to cover the per-wave serial
// LDS-wait -> MFMA-latency -> exp chain), but the pipelined dataflow holds
// ~190 unified regs/wave and the 128-reg cap at 4 w/SIMD spills (R1/R3/
// R11); cutting LDS amplification needs >=2 q-groups/wave -> o_acc alone
// >=128 regs -> 1 w/SIMD -> worse (R10). 2 w/SIMD + pipeline is the
// constrained optimum.
__global__ __launch_bounds__(THREADS, 2) void fattn_kernel(
    const float* __restrict__ Q, const bf16_t* __restrict__ Kb,
    const bf16_t* __restrict__ VT, float* __restrict__ Opart,
    float* __restrict__ Lpart, int kshift, int nit) {
  __shared__ __align__(16) bf16_t kt2[2][16][64][8];  // 32 KB [buf][d-chunk][key][8]
  __shared__ __align__(16) bf16_t vt3[3][8][128][8];  // 48 KB [buf][key-chunk][d][8]

  const int tid = (int)threadIdx.x;
  const int lane = tid & 63;
  const int w = tid >> 6;          // q-group 0..7
  const int h = lane >> 5;
  const int n32 = lane & 31;

  const int qt = (int)blockIdx.x >> kshift;
  const int sp = (int)blockIdx.x & ((1 << kshift) - 1);
  const int qbase = qt * BM;
  const int tile0 = sp * nit;          // first 64-key tile index

  const float SC2 = 0.08838834764831845f * 1.4426950408889634f; // (1/sqrt(128))*log2e

  // Q B-frags (n = n32 = q-row, k-dim = d), pre-scaled
  bf16x8 qf[8];
  {
    const float* qp = Q + (size_t)(qbase + w * 32 + n32) * HD + h * 8;
#pragma unroll
    for (int kk = 0; kk < 8; ++kk) {
      float4 a = *(const float4*)(qp + kk * 16);
      float4 b = *(const float4*)(qp + kk * 16 + 4);
      bf16x8 f;
      f[0] = (bf16_t)(a.x * SC2); f[1] = (bf16_t)(a.y * SC2);
      f[2] = (bf16_t)(a.z * SC2); f[3] = (bf16_t)(a.w * SC2);
      f[4] = (bf16_t)(b.x * SC2); f[5] = (bf16_t)(b.y * SC2);
      f[6] = (bf16_t)(b.z * SC2); f[7] = (bf16_t)(b.w * SC2);
      qf[kk] = f;
    }
  }

  f32x16 o_acc[4];   // O[32q x 128d]
#pragma unroll
  for (int i = 0; i < 4; ++i)
#pragma unroll
    for (int e = 0; e < 16; ++e) o_acc[i][e] = 0.f;
  float l_acc = 0.f;

  bf16x8 paA[4], paB[4];   // P A-frags for one 64-key tile (alternating)

  const int rr0 = w * 2;   // DMA region indices rr0, rr0+1

// exp -> pack -> permlane32_swap exchange -> ONE PV A-frag (16 keys).
// (fv0,fv2) = swap(sA,sC): fv0 = [sA.lo|sC.lo], fv2 = [sA.hi|sC.hi];
// (fv1,fv3) = swap(sB,sD). Verified against the shfl_xor mapping.
#define EXPPACK1(SACC, KK2, PDST_EXPR)                                     \
  {                                                                        \
    float pf[8];                                                           \
    _Pragma("unroll")                                                      \
    for (int j = 0; j < 8; ++j) pf[j] = exp2_fast((SACC)[8 * (KK2) + j]);  \
    l_acc += ((pf[0] + pf[1]) + (pf[2] + pf[3])) +                         \
             ((pf[4] + pf[5]) + (pf[6] + pf[7]));                          \
    bf16x2 p0, p1, p2, p3;                                                 \
    p0[0] = (bf16_t)pf[0]; p0[1] = (bf16_t)pf[1];                          \
    p1[0] = (bf16_t)pf[2]; p1[1] = (bf16_t)pf[3];                          \
    p2[0] = (bf16_t)pf[4]; p2[1] = (bf16_t)pf[5];                          \
    p3[0] = (bf16_t)pf[6]; p3[1] = (bf16_t)pf[7];                          \
    unsigned int sA = __builtin_bit_cast(unsigned int, p0);                \
    unsigned int sB = __builtin_bit_cast(unsigned int, p1);                \
    unsigned int sC = __builtin_bit_cast(unsigned int, p2);                \
    unsigned int sD = __builtin_bit_cast(unsigned int, p3);                \
    permswap32(sA, sC);                                                    \
    permswap32(sB, sD);                                                    \
    u32x4 fv;                                                              \
    fv[0] = sA; fv[1] = sB; fv[2] = sC; fv[3] = sD;                        \
    (PDST_EXPR) = __builtin_bit_cast(bf16x8, fv);                          \
  }

// one PV chunk: 16 keys (frag PP[C]) x all 128 d -> 4 MFMA
#define PVC(PP, C)                                                         \
  _Pragma("unroll")                                                        \
  for (int ot = 0; ot < 4; ++ot) {                                         \
    bf16x8 vb = *(const bf16x8*)&vt3[vp][(C) * 2 + h][ot * 32 + n32][0];   \
    o_acc[ot] = __builtin_amdgcn_mfma_f32_32x32x16_bf16(PP[C], vb, o_acc[ot], 0, 0, 0); \
  }

// pipelined body for iteration IT>=1: DMA(IT+1); QK^T(IT) from kt2[KC]
// (sacc0/sacc1 chains interleaved); then 4x [PV(IT-1) chunk || exp(IT)
// chunk]; barrier.  KC is a literal.
#define FBODY(IT, PPREV, PCUR, KC)                                         \
  {                                                                        \
    const int it_ = (IT);                                                  \
    if (it_ + 1 < nit) {                                                   \
      const int ntile = tile0 + it_ + 1;                                   \
      _Pragma("unroll")                                                    \
      for (int t = 0; t < 2; ++t) {                                        \
        const int rr = rr0 + t;                                            \
        load_lds16(Kb + ((size_t)(ntile * 16 + rr) * 64 + lane) * 8,       \
                   (char*)&kt2[(KC) ^ 1][0][0][0] + rr * 1024);            \
        load_lds16(VT + ((size_t)(ntile * 8 + (rr >> 1)) * 128 + (rr & 1) * 64 + lane) * 8, \
                   (char*)&vt3[vd][0][0][0] + rr * 1024);                  \
      }                                                                    \
    }                                                                      \
    f32x16 sacc0, sacc1;                                                   \
    _Pragma("unroll")                                                      \
    for (int e = 0; e < 16; ++e) { sacc0[e] = 0.f; sacc1[e] = 0.f; }       \
    _Pragma("unroll")                                                      \
    for (int kk = 0; kk < 8; ++kk) {                                       \
      bf16x8 af0 = *(const bf16x8*)&kt2[KC][2 * kk + h][n32][0];           \
      sacc0 = __builtin_amdgcn_mfma_f32_32x32x16_bf16(af0, qf[kk], sacc0, 0, 0, 0); \
      bf16x8 af1 = *(const bf16x8*)&kt2[KC][2 * kk + h][32 + n32][0];      \
      sacc1 = __builtin_amdgcn_mfma_f32_32x32x16_bf16(af1, qf[kk], sacc1, 0, 0, 0); \
    }                                                                      \
    PVC(PPREV, 0) EXPPACK1(sacc0, 0, PCUR[0])                              \
    PVC(PPREV, 1) EXPPACK1(sacc0, 1, PCUR[1])                              \
    PVC(PPREV, 2) EXPPACK1(sacc1, 0, PCUR[2])                              \
    PVC(PPREV, 3) EXPPACK1(sacc1, 1, PCUR[3])                              \
    vp = (vp + 1 == 3) ? 0 : vp + 1;                                       \
    vd = (vd + 1 == 3) ? 0 : vd + 1;                                       \
    __syncthreads();                                                       \
  }

  // ---- prologue: DMA tile0 -> kt[0], vt[0] ----
#pragma unroll
  for (int t = 0; t < 2; ++t) {
    const int rr = rr0 + t;
    load_lds16(Kb + ((size_t)(tile0 * 16 + rr) * 64 + lane) * 8,
               (char*)&kt2[0][0][0][0] + rr * 1024);
    load_lds16(VT + ((size_t)(tile0 * 8 + (rr >> 1)) * 128 + (rr & 1) * 64 + lane) * 8,
               (char*)&vt3[0][0][0][0] + rr * 1024);
  }
  __syncthreads();

  // ---- peel it=0: DMA tile1 -> kt[1], vt[1]; QK^T(0); exp -> paA ----
  {
    if (nit > 1) {
      const int ntile = tile0 + 1;
#pragma unroll
      for (int t = 0; t < 2; ++t) {
        const int rr = rr0 + t;
        load_lds16(Kb + ((size_t)(ntile * 16 + rr) * 64 + lane) * 8,
                   (char*)&kt2[1][0][0][0] + rr * 1024);
        load_lds16(VT + ((size_t)(ntile * 8 + (rr >> 1)) * 128 + (rr & 1) * 64 + lane) * 8,
                   (char*)&vt3[1][0][0][0] + rr * 1024);
      }
    }
    f32x16 sacc0, sacc1;
#pragma unroll
    for (int e = 0; e < 16; ++e) { sacc0[e] = 0.f; sacc1[e] = 0.f; }
#pragma unroll
    for (int kk = 0; kk < 8; ++kk) {
      bf16x8 af0 = *(const bf16x8*)&kt2[0][2 * kk + h][n32][0];
      sacc0 = __builtin_amdgcn_mfma_f32_32x32x16_bf16(af0, qf[kk], sacc0, 0, 0, 0);
      bf16x8 af1 = *(const bf16x8*)&kt2[0][2 * kk + h][32 + n32][0];
      sacc1 = __builtin_amdgcn_mfma_f32_32x32x16_bf16(af1, qf[kk], sacc1, 0, 0, 0);
    }
    EXPPACK1(sacc0, 0, paA[0])
    EXPPACK1(sacc0, 1, paA[1])
    EXPPACK1(sacc1, 0, paA[2])
    EXPPACK1(sacc1, 1, paA[3])
    __syncthreads();
  }

  int vp = 0;   // vt3 index holding tile (IT-1) for IT=1
  int vd = 2;   // vt3 index receiving tile (IT+1) for IT=1

  // nit is always even; bodies 1..nit-2 in pairs (KC literal by parity),
  // leftover body nit-1 (odd -> KC=1).
  for (int it = 1; it + 1 <= nit - 1; it += 2) {
    FBODY(it, paA, paB, 1)
    FBODY(it + 1, paB, paA, 0)
  }
  FBODY(nit - 1, paA, paB, 1)

  // ---- tail: PV(nit-1) using paB, vt3[vp] ----
#pragma unroll
  for (int C = 0; C < 4; ++C) {
#pragma unroll
    for (int ot = 0; ot < 4; ++ot) {
      bf16x8 vb = *(const bf16x8*)&vt3[vp][C * 2 + h][ot * 32 + n32][0];
      o_acc[ot] = __builtin_amdgcn_mfma_f32_32x32x16_bf16(paB[C], vb, o_acc[ot], 0, 0, 0);
    }
  }

#undef FBODY
#undef PVC
#undef EXPPACK1

  // ---- epilogue: O block store + L (all intra-wave) ----
  {
    float* op = Opart + ((size_t)sp * SEQ + qbase + w * 32) * HD;
#pragma unroll
    for (int ot = 0; ot < 4; ++ot)
#pragma unroll
      for (int reg = 0; reg < 16; ++reg) {
        const int row = (reg & 3) + 8 * (reg >> 2) + 4 * h;
        op[row * HD + ot * 32 + n32] = o_acc[ot][reg];
      }
    float l = l_acc + __shfl_xor(l_acc, 32);   // combine the two key-halves
    if (lane < 32)
      Lpart[(size_t)sp * SEQ + qbase + w * 32 + n32] = l;
  }
}

// ---------------- combine: out = sum_s O_s / sum_s l_s ----------------
__global__ __launch_bounds__(256) void combine_kernel(const float* __restrict__ Opart,
                                                      const float* __restrict__ Lpart,
                                                      float* __restrict__ out, int ksplit) {
  const int tid = (int)threadIdx.x;
  const int row = (int)blockIdx.x * 8 + (tid >> 5);
  const int c0 = (tid & 31) * 4;
  float lsum = 0.f;
  for (int s = 0; s < ksplit; ++s) lsum += Lpart[(size_t)s * SEQ + row];
  f32x4 acc;
#pragma unroll
  for (int e = 0; e < 4; ++e) acc[e] = 0.f;
  for (int s = 0; s < ksplit; ++s) {
    f32x4 o = *(const f32x4*)&Opart[((size_t)s * SEQ + row) * HD + c0];
#pragma unroll
    for (int e = 0; e < 4; ++e) acc[e] += o[e];
  }
  const float inv = 1.0f / lsum;
  f32x4 res;
#pragma unroll
  for (int e = 0; e < 4; ++e) res[e] = acc[e] * inv;
  *(f32x4*)&out[(size_t)row * HD + c0] = res;
}

extern "C" void kernel_launch(void* const* d_in, const int* in_sizes, int n_in,
                              void* d_out, int out_size, void* d_ws, size_t ws_size,
                              hipStream_t stream) {
  const float* Q = (const float*)d_in[0];
  const float* K = (const float*)d_in[1];
  const float* V = (const float*)d_in[2];
  float* out = (float*)d_out;

  int ksplit = 8, kshift = 3;
  while (ksplit > 1) {
    size_t need = (size_t)ksplit * SEQ * HD * 4
                + (size_t)ksplit * SEQ * 4
                + (size_t)SEQ * HD * 2 * 2;
    if (need <= ws_size) break;
    ksplit >>= 1; kshift--;
  }

  char* ws = (char*)d_ws;
  float* Opart = (float*)ws;
  float* Lpart = (float*)(ws + (size_t)ksplit * SEQ * HD * 4);
  bf16_t* Kb = (bf16_t*)(ws + (size_t)ksplit * SEQ * HD * 4 + (size_t)ksplit * SEQ * 4);
  bf16_t* VT = Kb + (size_t)SEQ * HD;

  const int nit = SEQ / (ksplit * BN);

  prep_kernel<<<768, 256, 0, stream>>>(K, V, Kb, VT);
  fattn_kernel<<<NQT * ksplit, THREADS, 0, stream>>>(Q, Kb, VT, Opart, Lpart, kshift, nit);
  combine_kernel<<<SEQ / 8, 256, 0, stream>>>(Opart, Lpart, out, ksplit);
}

// Round 17
// 108.636 us; speedup vs baseline: 1.0254x; 1.0254x over previous
//
#include <hip/hip_runtime.h>
#include <hip/hip_bf16.h>

#define SEQ 8192
#define HD 128
#define BM 256
#define BN 64
#define NQT (SEQ / BM)   // 32
#define THREADS 1024

typedef __bf16 bf16_t;
typedef __bf16 bf16x2 __attribute__((ext_vector_type(2)));
typedef __bf16 bf16x8 __attribute__((ext_vector_type(8)));
typedef float f32x4 __attribute__((ext_vector_type(4)));
typedef float f32x16 __attribute__((ext_vector_type(16)));
typedef unsigned int u32x4 __attribute__((ext_vector_type(4)));

#if __has_builtin(__builtin_amdgcn_exp2f)
__device__ inline float exp2_fast(float x) { return __builtin_amdgcn_exp2f(x); }
#else
__device__ inline float exp2_fast(float x) { return exp2f(x); }
#endif

// v_permlane32_swap_b32: a.hi32lanes <-> b.lo32lanes (mapping verified R9).
__device__ inline void permswap32(unsigned int& a, unsigned int& b) {
#if __has_builtin(__builtin_amdgcn_permlane32_swap)
  auto r = __builtin_amdgcn_permlane32_swap(a, b, false, false);
  a = (unsigned int)r[0];
  b = (unsigned int)r[1];
#else
  asm volatile("v_permlane32_swap_b32 %0, %1" : "+v"(a), "+v"(b));
#endif
}

// async global->LDS DMA, 16 B per lane; lds dest wave-uniform, HW adds lane*16
__device__ inline void load_lds16(const void* g, void* l) {
  __builtin_amdgcn_global_load_lds(
      (const __attribute__((address_space(1))) void*)g,
      (__attribute__((address_space(3))) void*)l, 16, 0, 0);
}

// Hand-rolled __syncthreads (s_barrier counts waves; safe in wave-uniform
// divergent branches as long as every wave executes the same count).
#define SYNC()                                                             \
  do {                                                                     \
    asm volatile("s_waitcnt vmcnt(0) lgkmcnt(0)\n\ts_barrier" ::: "memory"); \
    __builtin_amdgcn_sched_barrier(0);                                     \
  } while (0)

// ---------------- prep ----------------
// Kb blocked: [tile T][d-chunk c 0..15][key r 0..63][8]  = K[T*64+r][c*8+j]
// VT blocked: [tile T][key-chunk kc 0..7][d 0..127][8]   = V[T*64+kc*8+j][d]
__global__ __launch_bounds__(256) void prep_kernel(const float* __restrict__ K,
                                                   const float* __restrict__ V,
                                                   bf16_t* __restrict__ Kb,
                                                   bf16_t* __restrict__ VT) {
  const int b = (int)blockIdx.x;
  const int tid = (int)threadIdx.x;
  if (b < 256) {
    // V tile: 64 keys x 64 d, staged f32 in LDS (coalesced reads)
    __shared__ float tile[64][65];
    const int T = b & 127;
    const int d0 = (b >> 7) * 64;
    const int s0 = T * 64;
    const int r = tid >> 2;          // 0..63 (key)
    const int c0 = (tid & 3) * 16;   // d offset
#pragma unroll
    for (int j4 = 0; j4 < 4; ++j4) {
      float4 x = *(const float4*)&V[(size_t)(s0 + r) * HD + d0 + c0 + j4 * 4];
      tile[r][c0 + j4 * 4 + 0] = x.x;
      tile[r][c0 + j4 * 4 + 1] = x.y;
      tile[r][c0 + j4 * 4 + 2] = x.z;
      tile[r][c0 + j4 * 4 + 3] = x.w;
    }
    __syncthreads();
    const int d_l = tid & 63;
    const int kc0 = (tid >> 6) * 2;  // 0,2,4,6
#pragma unroll
    for (int k2 = 0; k2 < 2; ++k2) {
      const int kc = kc0 + k2;
      bf16x8 wv;
#pragma unroll
      for (int j = 0; j < 8; ++j) wv[j] = (bf16_t)tile[kc * 8 + j][d_l];
      *(bf16x8*)&VT[((size_t)(T * 8 + kc) * 128 + d0 + d_l) * 8] = wv;
    }
  } else {
    // K convert: one 16B chunk per thread
    const int base = (b - 256) * 2048 + tid * 8;   // flat over 8192*128
    const int row = base >> 7;
    const int c = (base >> 3) & 15;
    const int T = row >> 6;
    const int r = row & 63;
    float4 a = *(const float4*)&K[base];
    float4 cc = *(const float4*)&K[base + 4];
    bf16x8 f;
    f[0] = (bf16_t)a.x; f[1] = (bf16_t)a.y; f[2] = (bf16_t)a.z; f[3] = (bf16_t)a.w;
    f[4] = (bf16_t)cc.x; f[5] = (bf16_t)cc.y; f[6] = (bf16_t)cc.z; f[7] = (bf16_t)cc.w;
    *(bf16x8*)&Kb[((size_t)(T * 16 + c) * 64 + r) * 8] = f;
  }
}

// ---------------- main flash-attention kernel ----------------
// R17 = R16 with the pbuf buffer-stride bug fixed (was BUF*65536, i.e.
// double the real 32768-byte buffer stride -> odd-tile P landed past the
// 128 KB LDS allocation and was dropped; absmax 4.5 = half the keys lost).
// Producer-consumer WAVE SPECIALIZATION: BM=256, 16 waves (1024 thr),
// 1 block/CU:
//   waves 0-7  (QK role, qw=w):   QK^T(it) -> exp -> pack -> P A-frags
//                                 written to pbuf[it&1]; ~95 regs live.
//   waves 8-15 (PV role, qw=w-8): O += P(it-1) x V(it-1) from
//                                 pbuf[(it-1)&1], vt[(it-1)&1]; ~85 regs.
// Role states live in disjoint branches -> allocator overlays them ->
// both fit the 128-reg cap of launch_bounds(1024,4) -> 4 waves/SIMD of
// TLP (2x R9) without spill. One barrier per iteration; barrier counts
// match across roles (nit+1 each). LDS: K 2x16K + V 2x16K + P 2x32K
// = 128 KB (1 block/CU). DMA: QK waves stage K(it+1), PV waves stage
// V(it), each 2 regions/wave.
__global__ __launch_bounds__(THREADS, 4) void fattn_kernel(
    const float* __restrict__ Q, const bf16_t* __restrict__ Kb,
    const bf16_t* __restrict__ VT, float* __restrict__ Opart,
    float* __restrict__ Lpart, int kshift, int nit) {
  __shared__ __align__(16) bf16_t kt2[2][16][64][8];   // 32 KB [buf][d-chunk][key][8]
  __shared__ __align__(16) bf16_t vt2[2][8][128][8];   // 32 KB [buf][key-chunk][d][8]
  __shared__ __align__(16) char pbuf[2][8][4][64][16]; // 64 KB [buf][qw][chunk][lane][16B]

  const int tid = (int)threadIdx.x;
  const int lane = tid & 63;
  const int w = tid >> 6;          // 0..15
  const int qw = w & 7;            // q-group (32 rows) within BM=256
  const int h = lane >> 5;
  const int n32 = lane & 31;

  const int qt = (int)blockIdx.x >> kshift;
  const int sp = (int)blockIdx.x & ((1 << kshift) - 1);
  const int qbase = qt * BM;
  const int tile0 = sp * nit;          // first 64-key tile index

  const float SC2 = 0.08838834764831845f * 1.4426950408889634f; // (1/sqrt(128))*log2e

  char* const ktB = (char*)&kt2[0][0][0][0];
  char* const vtB = (char*)&vt2[0][0][0][0];
  char* const pbB = (char*)&pbuf[0][0][0][0][0];

#define DMA_K(TILE, BUF)                                                   \
  _Pragma("unroll")                                                        \
  for (int t = 0; t < 2; ++t) {                                            \
    const int rr = qw * 2 + t;                                             \
    load_lds16(Kb + ((size_t)((TILE) * 16 + rr) * 64 + lane) * 8,          \
               ktB + (BUF) * 16384 + rr * 1024);                           \
  }
#define DMA_V(TILE, BUF)                                                   \
  _Pragma("unroll")                                                        \
  for (int t = 0; t < 2; ++t) {                                            \
    const int rr = qw * 2 + t;                                             \
    load_lds16(VT + ((size_t)((TILE) * 8 + (rr >> 1)) * 128 + (rr & 1) * 64 + lane) * 8, \
               vtB + (BUF) * 16384 + rr * 1024);                           \
  }

// exp -> pack -> permlane32_swap -> P A-frag (16 keys) -> pbuf write.
// pbuf per-buffer stride = 8*4*64*16 = 32768 B (R16 bug: used 65536).
#define EXPPACKW(SACC, KK2, CIDX, BUF)                                     \
  {                                                                        \
    float pf[8];                                                           \
    _Pragma("unroll")                                                      \
    for (int j = 0; j < 8; ++j) pf[j] = exp2_fast((SACC)[8 * (KK2) + j]);  \
    l_acc += ((pf[0] + pf[1]) + (pf[2] + pf[3])) +                         \
             ((pf[4] + pf[5]) + (pf[6] + pf[7]));                          \
    bf16x2 p0, p1, p2, p3;                                                 \
    p0[0] = (bf16_t)pf[0]; p0[1] = (bf16_t)pf[1];                          \
    p1[0] = (bf16_t)pf[2]; p1[1] = (bf16_t)pf[3];                          \
    p2[0] = (bf16_t)pf[4]; p2[1] = (bf16_t)pf[5];                          \
    p3[0] = (bf16_t)pf[6]; p3[1] = (bf16_t)pf[7];                          \
    unsigned int sA = __builtin_bit_cast(unsigned int, p0);                \
    unsigned int sB = __builtin_bit_cast(unsigned int, p1);                \
    unsigned int sC = __builtin_bit_cast(unsigned int, p2);                \
    unsigned int sD = __builtin_bit_cast(unsigned int, p3);                \
    permswap32(sA, sC);                                                    \
    permswap32(sB, sD);                                                    \
    u32x4 fv;                                                              \
    fv[0] = sA; fv[1] = sB; fv[2] = sC; fv[3] = sD;                        \
    *(u32x4*)(pbB + (BUF) * 32768 + qw * 4096 + (CIDX) * 1024 + lane * 16) = fv; \
  }

// QK body for iteration IT (CUR = IT&1 literal): DMA K(IT+1); QK^T from
// kt2[CUR] (interleaved chains); exp -> pbuf[CUR]; barrier.
#define QKBODY(IT, CUR)                                                    \
  {                                                                        \
    const int it_ = (IT);                                                  \
    if (it_ + 1 < nit) { DMA_K(tile0 + it_ + 1, (CUR) ^ 1) }               \
    f32x16 sacc0, sacc1;                                                   \
    _Pragma("unroll")                                                      \
    for (int e = 0; e < 16; ++e) { sacc0[e] = 0.f; sacc1[e] = 0.f; }       \
    _Pragma("unroll")                                                      \
    for (int kk = 0; kk < 8; ++kk) {                                       \
      bf16x8 af0 = *(const bf16x8*)(ktB + (CUR) * 16384 + (2 * kk + h) * 1024 + n32 * 16); \
      sacc0 = __builtin_amdgcn_mfma_f32_32x32x16_bf16(af0, qf[kk], sacc0, 0, 0, 0); \
      bf16x8 af1 = *(const bf16x8*)(ktB + (CUR) * 16384 + (2 * kk + h) * 1024 + (32 + n32) * 16); \
      sacc1 = __builtin_amdgcn_mfma_f32_32x32x16_bf16(af1, qf[kk], sacc1, 0, 0, 0); \
    }                                                                      \
    EXPPACKW(sacc0, 0, 0, CUR)                                             \
    EXPPACKW(sacc0, 1, 1, CUR)                                             \
    EXPPACKW(sacc1, 0, 2, CUR)                                             \
    EXPPACKW(sacc1, 1, 3, CUR)                                             \
    SYNC();                                                                \
  }

// PV compute for tile PT (PBUF = PT&1 literal): O += P(PT) x V(PT).
#define PVCOMP(PBUF)                                                       \
  _Pragma("unroll")                                                        \
  for (int C = 0; C < 4; ++C) {                                            \
    bf16x8 pa = *(const bf16x8*)(pbB + (PBUF) * 32768 + qw * 4096 + C * 1024 + lane * 16); \
    _Pragma("unroll")                                                      \
    for (int ot = 0; ot < 4; ++ot) {                                       \
      bf16x8 vb = *(const bf16x8*)(vtB + (PBUF) * 16384 + (C * 2 + h) * 2048 + \
                                   (ot * 32 + n32) * 16);                  \
      o_acc[ot] = __builtin_amdgcn_mfma_f32_32x32x16_bf16(pa, vb, o_acc[ot], 0, 0, 0); \
    }                                                                      \
  }

// PV body for iteration IT>=1 (CUR = IT&1): DMA V(IT); PV(IT-1); barrier.
#define PVBODY(IT, CUR)                                                    \
  {                                                                        \
    DMA_V(tile0 + (IT), CUR)                                               \
    PVCOMP((CUR) ^ 1)                                                      \
    SYNC();                                                                \
  }

  if (w < 8) {
    // ================= QK producer role =================
    bf16x8 qf[8];
    {
      const float* qp = Q + (size_t)(qbase + qw * 32 + n32) * HD + h * 8;
#pragma unroll
      for (int kk = 0; kk < 8; ++kk) {
        float4 a = *(const float4*)(qp + kk * 16);
        float4 b = *(const float4*)(qp + kk * 16 + 4);
        bf16x8 f;
        f[0] = (bf16_t)(a.x * SC2); f[1] = (bf16_t)(a.y * SC2);
        f[2] = (bf16_t)(a.z * SC2); f[3] = (bf16_t)(a.w * SC2);
        f[4] = (bf16_t)(b.x * SC2); f[5] = (bf16_t)(b.y * SC2);
        f[6] = (bf16_t)(b.z * SC2); f[7] = (bf16_t)(b.w * SC2);
        qf[kk] = f;
      }
    }
    float l_acc = 0.f;

    DMA_K(tile0, 0)
    SYNC();   // prologue barrier (PV side matches)

    for (int it = 0; it < nit; it += 2) {   // nit even
      QKBODY(it, 0)
      QKBODY(it + 1, 1)
    }

    // epilogue: L (this wave covered all 64 keys of every tile)
    float l = l_acc + __shfl_xor(l_acc, 32);
    if (lane < 32)
      Lpart[(size_t)sp * SEQ + qbase + qw * 32 + n32] = l;
  } else {
    // ================= PV consumer role =================
    f32x16 o_acc[4];   // O[32q x 128d]
#pragma unroll
    for (int i = 0; i < 4; ++i)
#pragma unroll
      for (int e = 0; e < 16; ++e) o_acc[i][e] = 0.f;

    SYNC();   // match prologue barrier

    // it = 0: stage V(0); no P yet
    DMA_V(tile0, 0)
    SYNC();
    // it = 1: stage V(1); PV(0)
    PVBODY(1, 1)
    // it = 2 .. nit-1 (count nit-2, even)
    for (int it = 2; it < nit; it += 2) {
      PVBODY(it, 0)
      PVBODY(it + 1, 1)
    }
    // tail: PV(nit-1); P in pbuf[1], V in vt[1] (nit even -> nit-1 odd)
    PVCOMP(1)

    // epilogue: O block store
    float* op = Opart + ((size_t)sp * SEQ + qbase + qw * 32) * HD;
#pragma unroll
    for (int ot = 0; ot < 4; ++ot)
#pragma unroll
      for (int reg = 0; reg < 16; ++reg) {
        const int row = (reg & 3) + 8 * (reg >> 2) + 4 * h;
        op[row * HD + ot * 32 + n32] = o_acc[ot][reg];
      }
  }

#undef QKBODY
#undef PVBODY
#undef PVCOMP
#undef EXPPACKW
#undef DMA_K
#undef DMA_V
}

// ---------------- combine: out = sum_s O_s / sum_s l_s ----------------
__global__ __launch_bounds__(256) void combine_kernel(const float* __restrict__ Opart,
                                                      const float* __restrict__ Lpart,
                                                      float* __restrict__ out, int ksplit) {
  const int tid = (int)threadIdx.x;
  const int row = (int)blockIdx.x * 8 + (tid >> 5);
  const int c0 = (tid & 31) * 4;
  float lsum = 0.f;
  for (int s = 0; s < ksplit; ++s) lsum += Lpart[(size_t)s * SEQ + row];
  f32x4 acc;
#pragma unroll
  for (int e = 0; e < 4; ++e) acc[e] = 0.f;
  for (int s = 0; s < ksplit; ++s) {
    f32x4 o = *(const f32x4*)&Opart[((size_t)s * SEQ + row) * HD + c0];
#pragma unroll
    for (int e = 0; e < 4; ++e) acc[e] += o[e];
  }
  const float inv = 1.0f / lsum;
  f32x4 res;
#pragma unroll
  for (int e = 0; e < 4; ++e) res[e] = acc[e] * inv;
  *(f32x4*)&out[(size_t)row * HD + c0] = res;
}

extern "C" void kernel_launch(void* const* d_in, const int* in_sizes, int n_in,
                              void* d_out, int out_size, void* d_ws, size_t ws_size,
                              hipStream_t stream) {
  const float* Q = (const float*)d_in[0];
  const float* K = (const float*)d_in[1];
  const float* V = (const float*)d_in[2];
  float* out = (float*)d_out;

  int ksplit = 8, kshift = 3;
  while (ksplit > 1) {
    size_t need = (size_t)ksplit * SEQ * HD * 4
                + (size_t)ksplit * SEQ * 4
                + (size_t)SEQ * HD * 2 * 2;
    if (need <= ws_size) break;
    ksplit >>= 1; kshift--;
  }

  char* ws = (char*)d_ws;
  float* Opart = (float*)ws;
  float* Lpart = (float*)(ws + (size_t)ksplit * SEQ * HD * 4);
  bf16_t* Kb = (bf16_t*)(ws + (size_t)ksplit * SEQ * HD * 4 + (size_t)ksplit * SEQ * 4);
  bf16_t* VT = Kb + (size_t)SEQ * HD;

  const int nit = SEQ / (ksplit * BN);

  prep_kernel<<<768, 256, 0, stream>>>(K, V, Kb, VT);
  fattn_kernel<<<NQT * ksplit, THREADS, 0, stream>>>(Q, Kb, VT, Opart, Lpart, kshift, nit);
  combine_kernel<<<SEQ / 8, 256, 0, stream>>>(Opart, Lpart, out, ksplit);
}